// Round 19
// baseline (208.825 us; speedup 1.0000x reference)
//
#include <hip/hip_runtime.h>
#include <math.h>

namespace {

constexpr int NN = 50000;
constexpr int EE = 400000;
constexpr int CIN = 512;
constexpr int GH = 128;
constexpr int GO = 64;
constexpr int HEADS = 4;
constexpr int COUT = 32;
constexpr float EPS = 1e-5f;
constexpr int PBLK = (NN + 255) / 256;   // 196 = 4*49
constexpr int EDGEB = (EE + 255) / 256;  // 1563
constexpr int GM = (NN + 63) / 64;       // 782
constexpr int PREPB2 = 128 + 56;         // Mc(64) + Bv(64) + {W2,Wsk,Wfc}(56)
constexpr int INITB = PBLK + 256;        // cnt/deg-zero + W1 convert

typedef __attribute__((ext_vector_type(8))) _Float16 half8;
typedef __attribute__((ext_vector_type(4))) _Float16 half4;
typedef __attribute__((ext_vector_type(2))) _Float16 half2v;
typedef __attribute__((ext_vector_type(4))) float f32x4;

inline int cdiv(int a, int b) { return (a + b - 1) / b; }

// ---- init: zero cnt + deg, convert W1 -> W1p (f16 transposed) -----------
__global__ void k_init0(int* __restrict__ cnt, float* __restrict__ deg,
                        const float* __restrict__ W1,
                        _Float16* __restrict__ W1p) {
  if (blockIdx.x < PBLK) {
    int i = blockIdx.x * 256 + threadIdx.x;
    if (i < NN) { cnt[i] = 0; deg[i] = 0.0f; }
  } else {
    int i = (blockIdx.x - PBLK) * 256 + threadIdx.x;  // < 65536
    int k = i >> 7, f = i & 127;
    W1p[f * 512 + k] = (_Float16)W1[i];
  }
}

// ---- weight-prep device body (W1 excluded; done in k_init0) -------------
__device__ __forceinline__ void prep_body(
    int b, int tid,
    const float* __restrict__ Wq, const float* __restrict__ Wk,
    const float* __restrict__ bq, const float* __restrict__ Wv,
    const float* __restrict__ bv, const float* __restrict__ bsk,
    const float* __restrict__ W2, const float* __restrict__ Wsk,
    const float* __restrict__ Wfc,
    _Float16* __restrict__ Mcp, float* __restrict__ cvec,
    _Float16* __restrict__ Bcatp, float* __restrict__ bcomb,
    _Float16* __restrict__ W2p, _Float16* __restrict__ Wfcp) {
  if (b < 64) {
    const int i = b, col = tid, h = col >> 6, j = col & 63;
    float acc = 0.f;
    for (int t = 0; t < 64; ++t)
      acc += Wq[i * 256 + h * 64 + t] * Wk[j * 256 + h * 64 + t];
    Mcp[col * 64 + i] = (_Float16)(0.125f * acc);
    if (i == 0) {
      float c = 0.f;
      for (int t = 0; t < 64; ++t) c += bq[h * 64 + t] * Wk[j * 256 + h * 64 + t];
      cvec[col] = 0.125f * c;
    }
  } else if (b < 128) {
    const int idx = (b - 64) * 256 + tid;
    const int rr = idx >> 6, t = idx & 63;
    const int h = rr >> 6, c = rr & 63;
    Bcatp[(size_t)t * 320 + 64 + rr] = (_Float16)(0.25f * Wv[c * 256 + h * 64 + t]);
    if (b == 64 && tid < 64) {
      float s = 0.f;
#pragma unroll
      for (int h2 = 0; h2 < 4; ++h2) s += bv[h2 * 64 + tid];
      bcomb[tid] = bsk[tid] + 0.25f * s;
    }
  } else {
    const int i = (b - 128) * 256 + tid;  // < 14336
    if (i < 8192) { int k = i >> 6, f = i & 63; W2p[f * 128 + k] = (_Float16)W2[i]; }
    else if (i < 12288) { int rel = i - 8192; int k = rel >> 6, f = rel & 63; Bcatp[f * 320 + k] = (_Float16)Wsk[rel]; }
    else { int rel = i - 12288; int k = rel >> 5, f = rel & 31; Wfcp[f * 64 + k] = (_Float16)Wfc[rel]; }
  }
}

// ---- hybrid MFMA GEMM body: BM=64, 2-deep ping-pong pipeline ------------
// AF32C: A fp32, converted to single f16 at LDS store (1 MFMA/product).
template <int F, int K, int LDA, bool AF32C, bool OUTF32>
__device__ __forceinline__
void hgemm_body(int bid, const void* __restrict__ Av,
                const _Float16* __restrict__ Bp, const float* __restrict__ bias,
                void* __restrict__ Cv, int M) {
  constexpr int MI = 4;
  constexpr int NR = F / 64;
  constexpr int FW = F / 4;
  constexpr int NT = K / 64;

  __shared__ _Float16 Ah[64 * 64];

  const int tid = threadIdx.x;
  const int lane = tid & 63;
  const int wc = tid >> 6;
  const int l15 = lane & 15, lhi = lane >> 4;
  const int m0 = bid * 64;
  const int r = tid >> 2, ch = tid & 3;
  const int gr = min(m0 + r, M - 1);

  f32x4 acc[MI][NR];
#pragma unroll
  for (int mi = 0; mi < MI; ++mi)
#pragma unroll
    for (int ni = 0; ni < NR; ++ni) acc[mi][ni] = (f32x4)0.0f;

  const int sbase = r * 128 + ch * 32;
  const int ssw = (r & 7) << 4;

  auto COMPUTE = [&](int k0) {
#pragma unroll
    for (int ks = 0; ks < 2; ++ks) {
      half8 ah[MI];
#pragma unroll
      for (int mi = 0; mi < MI; ++mi) {
        const int row = mi * 16 + l15;
        const int off = (row * 128 + (ks * 32 + lhi * 8) * 2) ^ ((row & 7) << 4);
        ah[mi] = *reinterpret_cast<const half8*>((const char*)Ah + off);
      }
#pragma unroll
      for (int ni = 0; ni < NR; ++ni) {
        const int col = wc * FW + ni * 16 + l15;
        const half8 bf = *reinterpret_cast<const half8*>(
            Bp + (size_t)col * K + k0 + ks * 32 + lhi * 8);
#pragma unroll
        for (int mi = 0; mi < MI; ++mi)
          acc[mi][ni] = __builtin_amdgcn_mfma_f32_16x16x32_f16(ah[mi], bf, acc[mi][ni], 0, 0, 0);
      }
    }
  };

  float xfA[16], xfB[16];
  half8 xhA0, xhA1, xhB0, xhB1;

  auto LOADA = [&](int kk) {
    if constexpr (AF32C) {
      const float4* src = reinterpret_cast<const float4*>(
          (const float*)Av + (size_t)gr * LDA + kk + ch * 16);
#pragma unroll
      for (int i = 0; i < 4; ++i) {
        float4 f = src[i];
        xfA[i * 4 + 0] = f.x; xfA[i * 4 + 1] = f.y;
        xfA[i * 4 + 2] = f.z; xfA[i * 4 + 3] = f.w;
      }
    } else {
      const half8* src = reinterpret_cast<const half8*>(
          (const _Float16*)Av + (size_t)gr * LDA + kk + ch * 16);
      xhA0 = src[0]; xhA1 = src[1];
    }
  };
  auto LOADB = [&](int kk) {
    if constexpr (AF32C) {
      const float4* src = reinterpret_cast<const float4*>(
          (const float*)Av + (size_t)gr * LDA + kk + ch * 16);
#pragma unroll
      for (int i = 0; i < 4; ++i) {
        float4 f = src[i];
        xfB[i * 4 + 0] = f.x; xfB[i * 4 + 1] = f.y;
        xfB[i * 4 + 2] = f.z; xfB[i * 4 + 3] = f.w;
      }
    } else {
      const half8* src = reinterpret_cast<const half8*>(
          (const _Float16*)Av + (size_t)gr * LDA + kk + ch * 16);
      xhB0 = src[0]; xhB1 = src[1];
    }
  };

  auto STOREA = [&]() {
    if constexpr (AF32C) {
      half8 v0, v1;
#pragma unroll
      for (int i = 0; i < 8; ++i) v0[i] = (_Float16)xfA[i];
#pragma unroll
      for (int i = 0; i < 8; ++i) v1[i] = (_Float16)xfA[8 + i];
      *reinterpret_cast<half8*>((char*)Ah + (sbase ^ ssw)) = v0;
      *reinterpret_cast<half8*>((char*)Ah + ((sbase + 16) ^ ssw)) = v1;
    } else {
      *reinterpret_cast<half8*>((char*)Ah + (sbase ^ ssw)) = xhA0;
      *reinterpret_cast<half8*>((char*)Ah + ((sbase + 16) ^ ssw)) = xhA1;
    }
  };
  auto STOREB = [&]() {
    if constexpr (AF32C) {
      half8 v0, v1;
#pragma unroll
      for (int i = 0; i < 8; ++i) v0[i] = (_Float16)xfB[i];
#pragma unroll
      for (int i = 0; i < 8; ++i) v1[i] = (_Float16)xfB[8 + i];
      *reinterpret_cast<half8*>((char*)Ah + (sbase ^ ssw)) = v0;
      *reinterpret_cast<half8*>((char*)Ah + ((sbase + 16) ^ ssw)) = v1;
    } else {
      *reinterpret_cast<half8*>((char*)Ah + (sbase ^ ssw)) = xhB0;
      *reinterpret_cast<half8*>((char*)Ah + ((sbase + 16) ^ ssw)) = xhB1;
    }
  };

  LOADA(0);
  if constexpr (NT > 1) LOADB(64);

#pragma unroll
  for (int t = 0; t < NT; ++t) {
    if ((t & 1) == 0) STOREA(); else STOREB();
    __syncthreads();
    if ((t & 1) == 0) {
      if (t + 2 < NT) LOADA((t + 2) * 64);
    } else {
      if (t + 2 < NT) LOADB((t + 2) * 64);
    }
    COMPUTE(t * 64);
    __syncthreads();
  }

#pragma unroll
  for (int ni = 0; ni < NR; ++ni) {
    const int col = wc * FW + ni * 16 + l15;
    const float bvv = bias ? bias[col] : 0.0f;
#pragma unroll
    for (int mi = 0; mi < MI; ++mi) {
#pragma unroll
      for (int rr = 0; rr < 4; ++rr) {
        const int orow = m0 + mi * 16 + lhi * 4 + rr;
        if (orow < M) {
          float val = acc[mi][ni][rr] + bvv;
          if (OUTF32)
            ((float*)Cv)[(size_t)orow * F + col] = val;
          else
            ((_Float16*)Cv)[(size_t)orow * F + col] = (_Float16)val;
        }
      }
    }
  }
}

template <int F, int K, int LDA, bool AF32C, bool OUTF32>
__launch_bounds__(256) __global__
void hgemm(const void* __restrict__ Av, const _Float16* __restrict__ Bp,
           const float* __restrict__ bias, void* __restrict__ Cv, int M) {
  hgemm_body<F, K, LDA, AF32C, OUTF32>(blockIdx.x, Av, Bp, bias, Cv, M);
}

// ---- fused: GEMM1 || edge pass (rank + weighted deg) || weight prep -----
__launch_bounds__(256) __global__
void k_edgegemm1(const float* __restrict__ x, const _Float16* __restrict__ W1p,
                 _Float16* __restrict__ h1f, int M,
                 const int* __restrict__ ei, const float* __restrict__ ew,
                 int* __restrict__ cnt, float* __restrict__ deg,
                 int* __restrict__ rank,
                 const float* __restrict__ Wq, const float* __restrict__ Wk,
                 const float* __restrict__ bq, const float* __restrict__ Wv,
                 const float* __restrict__ bv, const float* __restrict__ bsk,
                 const float* __restrict__ W2, const float* __restrict__ Wsk,
                 const float* __restrict__ Wfc,
                 _Float16* __restrict__ Mcp, float* __restrict__ cvec,
                 _Float16* __restrict__ Bcatp, float* __restrict__ bcomb,
                 _Float16* __restrict__ W2p, _Float16* __restrict__ Wfcp) {
  if (blockIdx.x < GM) {
    hgemm_body<128, 512, 512, true, false>(blockIdx.x, x, W1p, nullptr, h1f, M);
  } else if (blockIdx.x < GM + EDGEB) {
    int e = (blockIdx.x - GM) * 256 + threadIdx.x;
    if (e < EE) {
      int d = ei[EE + e];
      atomicAdd(&deg[d], ew[e]);
      rank[e] = atomicAdd(&cnt[d], 1);
    }
  } else {
    prep_body(blockIdx.x - GM - EDGEB, threadIdx.x, Wq, Wk, bq, Wv, bv, bsk,
              W2, Wsk, Wfc, Mcp, cvec, Bcatp, bcomb, W2p, Wfcp);
  }
}

// ---- node pass 1: dinv finalize + block-scan partials + block histogram -
__global__ void k_node1(const int* __restrict__ cnt, float* __restrict__ dinv,
                        int* __restrict__ part, int* __restrict__ bsum,
                        int* __restrict__ blkhist) {
  __shared__ int wsm[4];
  __shared__ int lh[64];
  const int tid = threadIdx.x, lane = tid & 63, wv = tid >> 6;
  const int i = blockIdx.x * 256 + tid;
  if (tid < 64) lh[tid] = 0;
  __syncthreads();
  int v = (i < NN) ? cnt[i] : 0;
  if (i < NN) {
    dinv[i] = rsqrtf(dinv[i] + 1.0f);  // deg stored in dinv buffer
    atomicAdd(&lh[min(v, 63)], 1);
  }
  int x = v;
#pragma unroll
  for (int s = 1; s < 64; s <<= 1) {
    int t = __shfl_up(x, s);
    if (lane >= s) x += t;
  }
  if (lane == 63) wsm[wv] = x;
  __syncthreads();
  if (tid == 0) {
    int r = 0;
#pragma unroll
    for (int j = 0; j < 4; ++j) { int t = wsm[j]; wsm[j] = r; r += t; }
    bsum[blockIdx.x] = r;
  }
  __syncthreads();
  if (i < NN) part[i] = wsm[wv] + x - v;
  if (tid < 64) blkhist[blockIdx.x * 64 + tid] = lh[tid];
}

// ---- fused small pass ---------------------------------------------------
__launch_bounds__(256) __global__
void k_small(int* __restrict__ bsum, int* __restrict__ ro,
             const int* __restrict__ blkhist, int* __restrict__ blkoff) {
  __shared__ int wsm[4];
  __shared__ int qsum[4][64];
  const int tid = threadIdx.x, lane = tid & 63, wv = tid >> 6;
  {
    int v = (tid < PBLK) ? bsum[tid] : 0;
    int x = v;
#pragma unroll
    for (int s = 1; s < 64; s <<= 1) {
      int t = __shfl_up(x, s);
      if (lane >= s) x += t;
    }
    if (lane == 63) wsm[wv] = x;
    __syncthreads();
    if (tid == 0) {
      int r = 0;
#pragma unroll
      for (int j = 0; j < 4; ++j) { int t = wsm[j]; wsm[j] = r; r += t; }
      ro[NN] = r;
    }
    __syncthreads();
    if (tid < PBLK) bsum[tid] = wsm[wv] + x - v;
  }
  const int c0 = wv * 49, c1 = c0 + 49;
  {
    int qs = 0;
    int k = c0;
    for (; k + 4 <= c1; k += 4) {
      int a = blkhist[(k + 0) * 64 + lane];
      int b = blkhist[(k + 1) * 64 + lane];
      int c = blkhist[(k + 2) * 64 + lane];
      int d = blkhist[(k + 3) * 64 + lane];
      qs += (a + b) + (c + d);
    }
    for (; k < c1; ++k) qs += blkhist[k * 64 + lane];
    qsum[wv][lane] = qs;
  }
  __syncthreads();
  int tot = qsum[0][lane] + qsum[1][lane] + qsum[2][lane] + qsum[3][lane];
  int x = tot;
#pragma unroll
  for (int s = 1; s < 64; s <<= 1) {
    int t = __shfl_up(x, s);
    if (lane >= s) x += t;
  }
  int run = x - tot;
  for (int q = 0; q < wv; ++q) run += qsum[q][lane];
  int k = c0;
  for (; k + 4 <= c1; k += 4) {
    int a = blkhist[(k + 0) * 64 + lane];
    int b = blkhist[(k + 1) * 64 + lane];
    int c = blkhist[(k + 2) * 64 + lane];
    int d = blkhist[(k + 3) * 64 + lane];
    blkoff[(k + 0) * 64 + lane] = run;
    blkoff[(k + 1) * 64 + lane] = run + a;
    blkoff[(k + 2) * 64 + lane] = run + a + b;
    blkoff[(k + 3) * 64 + lane] = run + a + b + c;
    run += (a + b) + (c + d);
  }
  for (; k < c1; ++k) {
    int c = blkhist[k * 64 + lane];
    blkoff[k * 64 + lane] = run;
    run += c;
  }
}

// ---- fused: node2 (ro finalize + perm) || CSR fill (on-the-fly ro) ------
__launch_bounds__(256) __global__
void k_nodefill(const int* __restrict__ part, const int* __restrict__ bsum,
                int* __restrict__ ro, const int* __restrict__ cnt,
                const int* __restrict__ blkoff, int* __restrict__ perm,
                const int* __restrict__ ei, const float* __restrict__ w,
                const int* __restrict__ rank, int2* __restrict__ csrp) {
  if (blockIdx.x < PBLK) {
    __shared__ int lcur[64];
    const int tid = threadIdx.x;
    const int i = blockIdx.x * 256 + tid;
    if (tid < 64) lcur[tid] = 0;
    if (i < NN) ro[i] = part[i] + bsum[i >> 8];
    __syncthreads();
    if (i < NN) {
      int b = min(cnt[i], 63);
      int r = atomicAdd(&lcur[b], 1);
      perm[blkoff[blockIdx.x * 64 + b] + r] = i;
    }
  } else {
    int e = (blockIdx.x - PBLK) * 256 + threadIdx.x;
    if (e < EE) {
      int d = ei[EE + e];
      int p = part[d] + bsum[d >> 8] + rank[e];
      int2 pk;
      pk.x = ei[e];
      pk.y = __float_as_int(w[e]);
      csrp[p] = pk;
    }
  }
}

// ---- fused final: agg = [z|u]@Bcat + bcomb, BN+ReLU; out = agg@Wfc + bfc
__launch_bounds__(256) __global__
void k_aggfc(const _Float16* __restrict__ zu, const _Float16* __restrict__ Bcatp,
             const float* __restrict__ bcomb, const _Float16* __restrict__ Wfcp,
             const float* __restrict__ bfc, float* __restrict__ out, int M,
             const float* __restrict__ gt, const float* __restrict__ bet,
             const float* __restrict__ mt, const float* __restrict__ vt) {
  __shared__ _Float16 Ah[64 * 64];
  __shared__ _Float16 Gs[64 * 64];

  const int tid = threadIdx.x;
  const int lane = tid & 63;
  const int wid = tid >> 6;
  const int l15 = lane & 15, lhi = lane >> 4;
  const int m0 = blockIdx.x * 64;
  const int r = tid >> 2, ch = tid & 3;
  const int gr = min(m0 + r, M - 1);

  f32x4 acc[4];
#pragma unroll
  for (int mi = 0; mi < 4; ++mi) acc[mi] = (f32x4)0.0f;

  half8 xhA0, xhA1, xhB0, xhB1;
  auto LOADA = [&](int kk) {
    const half8* src = reinterpret_cast<const half8*>(
        zu + (size_t)gr * 320 + kk + ch * 16);
    xhA0 = src[0]; xhA1 = src[1];
  };
  auto LOADB = [&](int kk) {
    const half8* src = reinterpret_cast<const half8*>(
        zu + (size_t)gr * 320 + kk + ch * 16);
    xhB0 = src[0]; xhB1 = src[1];
  };
  const int sbase = r * 128 + ch * 32;
  const int ssw = (r & 7) << 4;
  auto STOREA = [&]() {
    *reinterpret_cast<half8*>((char*)Ah + (sbase ^ ssw)) = xhA0;
    *reinterpret_cast<half8*>((char*)Ah + ((sbase + 16) ^ ssw)) = xhA1;
  };
  auto STOREB = [&]() {
    *reinterpret_cast<half8*>((char*)Ah + (sbase ^ ssw)) = xhB0;
    *reinterpret_cast<half8*>((char*)Ah + ((sbase + 16) ^ ssw)) = xhB1;
  };

  LOADA(0);
  LOADB(64);
#pragma unroll
  for (int t = 0; t < 5; ++t) {
    if ((t & 1) == 0) STOREA(); else STOREB();
    __syncthreads();
    if ((t & 1) == 0) {
      if (t + 2 < 5) LOADA((t + 2) * 64);
    } else {
      if (t + 2 < 5) LOADB((t + 2) * 64);
    }
    const int k0 = t * 64;
#pragma unroll
    for (int ks = 0; ks < 2; ++ks) {
      half8 ah[4];
#pragma unroll
      for (int mi = 0; mi < 4; ++mi) {
        const int row = mi * 16 + l15;
        const int off = (row * 128 + (ks * 32 + lhi * 8) * 2) ^ ((row & 7) << 4);
        ah[mi] = *reinterpret_cast<const half8*>((const char*)Ah + off);
      }
      const int col = wid * 16 + l15;
      const half8 bf = *reinterpret_cast<const half8*>(
          Bcatp + (size_t)col * 320 + k0 + ks * 32 + lhi * 8);
#pragma unroll
      for (int mi = 0; mi < 4; ++mi)
        acc[mi] = __builtin_amdgcn_mfma_f32_16x16x32_f16(ah[mi], bf, acc[mi], 0, 0, 0);
    }
    __syncthreads();
  }

  {
    const int col = wid * 16 + l15;
    const float bns = gt[col] * rsqrtf(vt[col] + EPS);
    const float bnb = bet[col], bnm = mt[col], bco = bcomb[col];
#pragma unroll
    for (int mi = 0; mi < 4; ++mi) {
#pragma unroll
      for (int rr = 0; rr < 4; ++rr) {
        const int row = mi * 16 + lhi * 4 + rr;
        float val = acc[mi][rr] + bco;
        val = (val - bnm) * bns + bnb;
        val = val > 0.f ? val : 0.f;
        const int boff = (row * 128 + col * 2) ^ ((row & 7) << 4);
        *reinterpret_cast<_Float16*>((char*)Gs + boff) = (_Float16)val;
      }
    }
  }
  __syncthreads();

  f32x4 acc2[2];
#pragma unroll
  for (int ni = 0; ni < 2; ++ni) acc2[ni] = (f32x4)0.0f;
#pragma unroll
  for (int ks = 0; ks < 2; ++ks) {
    const int row = wid * 16 + l15;
    const int off = (row * 128 + (ks * 32 + lhi * 8) * 2) ^ ((row & 7) << 4);
    const half8 ag = *reinterpret_cast<const half8*>((const char*)Gs + off);
#pragma unroll
    for (int ni = 0; ni < 2; ++ni) {
      const int col = ni * 16 + l15;
      const half8 bf = *reinterpret_cast<const half8*>(
          Wfcp + (size_t)col * 64 + ks * 32 + lhi * 8);
      acc2[ni] = __builtin_amdgcn_mfma_f32_16x16x32_f16(ag, bf, acc2[ni], 0, 0, 0);
    }
  }
#pragma unroll
  for (int ni = 0; ni < 2; ++ni) {
    const int col = ni * 16 + l15;
#pragma unroll
    for (int rr = 0; rr < 4; ++rr) {
      const int orow = m0 + wid * 16 + lhi * 4 + rr;
      if (orow < M) out[(size_t)orow * COUT + col] = acc2[ni][rr] + bfc[col];
    }
  }
}

// ---- GCN propagate: on-the-fly norm (dinv[s]*w), final scale by dinv[d] -
__launch_bounds__(256) __global__
void k_gcn128(const int* __restrict__ ro, const int2* __restrict__ csrp,
              const int* __restrict__ perm, const _Float16* __restrict__ h,
              const float* __restrict__ dinv, const float* __restrict__ bias,
              const float* __restrict__ g, const float* __restrict__ be,
              const float* __restrict__ m, const float* __restrict__ v,
              _Float16* __restrict__ out) {
  const int idx = blockIdx.x * 4 + (threadIdx.x >> 6);
  const int lane = threadIdx.x & 63;
  if (idx >= NN) return;
  const int wid = perm[idx];
  const float di = dinv[wid];
  const int p0 = ro[wid], p1 = ro[wid + 1];

  half2v sv = *reinterpret_cast<const half2v*>(h + (size_t)wid * 128 + lane * 2);
  float2 a[4];
  a[0] = make_float2((float)sv[0] * di, (float)sv[1] * di);
  a[1] = make_float2(0.f, 0.f);
  a[2] = make_float2(0.f, 0.f);
  a[3] = make_float2(0.f, 0.f);
  int p = p0;
  for (; p + 8 <= p1; p += 8) {
    int2 pk[8];
#pragma unroll
    for (int j = 0; j < 8; ++j) pk[j] = csrp[p + j];
    float ds[8];
#pragma unroll
    for (int j = 0; j < 8; ++j) ds[j] = dinv[pk[j].x];
    half2v hv[8];
#pragma unroll
    for (int j = 0; j < 8; ++j)
      hv[j] = *reinterpret_cast<const half2v*>(h + (size_t)pk[j].x * 128 + lane * 2);
#pragma unroll
    for (int j = 0; j < 8; ++j) {
      float c = ds[j] * __int_as_float(pk[j].y);
      a[j & 3].x += c * (float)hv[j][0];
      a[j & 3].y += c * (float)hv[j][1];
    }
  }
  for (; p + 4 <= p1; p += 4) {
    int2 pk[4];
#pragma unroll
    for (int j = 0; j < 4; ++j) pk[j] = csrp[p + j];
    float ds[4];
#pragma unroll
    for (int j = 0; j < 4; ++j) ds[j] = dinv[pk[j].x];
    half2v hv[4];
#pragma unroll
    for (int j = 0; j < 4; ++j)
      hv[j] = *reinterpret_cast<const half2v*>(h + (size_t)pk[j].x * 128 + lane * 2);
#pragma unroll
    for (int j = 0; j < 4; ++j) {
      float c = ds[j] * __int_as_float(pk[j].y);
      a[j].x += c * (float)hv[j][0];
      a[j].y += c * (float)hv[j][1];
    }
  }
  for (; p < p1; ++p) {
    int2 pk = csrp[p];
    float c = dinv[pk.x] * __int_as_float(pk.y);
    half2v hv = *reinterpret_cast<const half2v*>(h + (size_t)pk.x * 128 + lane * 2);
    a[1].x += c * (float)hv[0]; a[1].y += c * (float)hv[1];
  }
  float ax = ((a[0].x + a[1].x) + (a[2].x + a[3].x)) * di;
  float ay = ((a[0].y + a[1].y) + (a[2].y + a[3].y)) * di;
  float2 gg = reinterpret_cast<const float2*>(g)[lane];
  float2 bb = reinterpret_cast<const float2*>(be)[lane];
  float2 mm = reinterpret_cast<const float2*>(m)[lane];
  float2 vv = reinterpret_cast<const float2*>(v)[lane];
  float2 bi = reinterpret_cast<const float2*>(bias)[lane];
  float s0 = gg.x * rsqrtf(vv.x + EPS);
  float s1 = gg.y * rsqrtf(vv.y + EPS);
  float y0 = (ax + bi.x - mm.x) * s0 + bb.x;
  float y1 = (ay + bi.y - mm.y) * s1 + bb.y;
  half2v o;
  o[0] = (_Float16)(y0 > 0.f ? y0 : 0.f);
  o[1] = (_Float16)(y1 > 0.f ? y1 : 0.f);
  *reinterpret_cast<half2v*>(out + (size_t)wid * 128 + lane * 2) = o;
}

// F=64 variant: writes z into zu[:,0:64] (stride 320)
__launch_bounds__(256) __global__
void k_gcn64(const int* __restrict__ ro, const int2* __restrict__ csrp,
             const int* __restrict__ perm, const _Float16* __restrict__ h,
             const float* __restrict__ dinv, const float* __restrict__ bias,
             const float* __restrict__ g, const float* __restrict__ be,
             const float* __restrict__ m, const float* __restrict__ v,
             _Float16* __restrict__ zu) {
  const int idx = blockIdx.x * 4 + (threadIdx.x >> 6);
  const int lane = threadIdx.x & 63;
  if (idx >= NN) return;
  const int wid = perm[idx];
  const float di = dinv[wid];
  const int p0 = ro[wid], p1 = ro[wid + 1];

  float a[4];
  a[0] = (float)h[(size_t)wid * 64 + lane] * di;
  a[1] = 0.f; a[2] = 0.f; a[3] = 0.f;
  int p = p0;
  for (; p + 8 <= p1; p += 8) {
    int2 pk[8];
#pragma unroll
    for (int j = 0; j < 8; ++j) pk[j] = csrp[p + j];
    float ds[8];
#pragma unroll
    for (int j = 0; j < 8; ++j) ds[j] = dinv[pk[j].x];
    float hv[8];
#pragma unroll
    for (int j = 0; j < 8; ++j) hv[j] = (float)h[(size_t)pk[j].x * 64 + lane];
#pragma unroll
    for (int j = 0; j < 8; ++j) a[j & 3] += ds[j] * __int_as_float(pk[j].y) * hv[j];
  }
  for (; p + 4 <= p1; p += 4) {
    int2 pk[4];
#pragma unroll
    for (int j = 0; j < 4; ++j) pk[j] = csrp[p + j];
    float ds[4];
#pragma unroll
    for (int j = 0; j < 4; ++j) ds[j] = dinv[pk[j].x];
    float hv[4];
#pragma unroll
    for (int j = 0; j < 4; ++j) hv[j] = (float)h[(size_t)pk[j].x * 64 + lane];
#pragma unroll
    for (int j = 0; j < 4; ++j) a[j] += ds[j] * __int_as_float(pk[j].y) * hv[j];
  }
  for (; p < p1; ++p) {
    int2 pk = csrp[p];
    a[1] += dinv[pk.x] * __int_as_float(pk.y) * (float)h[(size_t)pk.x * 64 + lane];
  }
  float av = ((a[0] + a[1]) + (a[2] + a[3])) * di;
  float sc = g[lane] * rsqrtf(v[lane] + EPS);
  float y = (av + bias[lane] - m[lane]) * sc + be[lane];
  zu[(size_t)wid * 320 + lane] = (_Float16)(y > 0.f ? y : 0.f);
}

// ---- fused edge-softmax attention, 2-wide software pipeline -------------
__launch_bounds__(256) __global__
void k_attn(const int* __restrict__ ro, const int2* __restrict__ csrp,
            const int* __restrict__ perm, _Float16* zu,
            const _Float16* __restrict__ qpp) {
  const int wave = blockIdx.x * 4 + (threadIdx.x >> 6);
  const int lane = threadIdx.x & 63;
  const int g = lane >> 4;
  const int t = lane & 15;
  const bool bit3 = (t & 8) != 0, bit2 = (t & 4) != 0;

  const int idx = wave * 4 + g;
  const bool valid = idx < NN;
  const int dst = perm[valid ? idx : 0];

  float4 q[4];
#pragma unroll
  for (int h = 0; h < 4; ++h) {
    half4 qh = *reinterpret_cast<const half4*>(qpp + (size_t)dst * 256 + h * 64 + t * 4);
    q[h] = make_float4((float)qh[0], (float)qh[1], (float)qh[2], (float)qh[3]);
  }

  float4 ua[4];
  float den[4];
#pragma unroll
  for (int h = 0; h < 4; ++h) {
    ua[h] = make_float4(0.f, 0.f, 0.f, 0.f);
    den[h] = 0.f;
  }

  int p = valid ? ro[dst] : 0;
  const int pend = valid ? ro[dst + 1] : 0;

  auto reduce4 = [&](float pa0, float pa1, float pa2, float pa3,
                     float& o0, float& o1, float& o2, float& o3) {
    float send1 = bit3 ? pa0 : pa2;
    float recv1 = __shfl_xor(send1, 8);
    float a0 = (bit3 ? pa2 : pa0) + recv1;
    float send2 = bit3 ? pa1 : pa3;
    float recv2 = __shfl_xor(send2, 8);
    float a1 = (bit3 ? pa3 : pa1) + recv2;
    float send3 = bit2 ? a0 : a1;
    float recv3 = __shfl_xor(send3, 4);
    float b = (bit2 ? a1 : a0) + recv3;
    b += __shfl_xor(b, 2);
    b += __shfl_xor(b, 1);
    float r4 = __shfl_xor(b, 4);
    float r8 = __shfl_xor(b, 8);
    float r84 = __shfl_xor(r4, 8);
    o0 = bit3 ? (bit2 ? r84 : r8) : (bit2 ? r4 : b);
    o1 = bit3 ? (bit2 ? r8 : r84) : (bit2 ? b : r4);
    o2 = bit3 ? (bit2 ? r4 : b) : (bit2 ? r84 : r8);
    o3 = bit3 ? (bit2 ? b : r4) : (bit2 ? r8 : r84);
  };

  int sA = csrp[min(p, EE - 1)].x;
  int sB = csrp[min(p + 1, EE - 1)].x;
  half4 znA = *reinterpret_cast<const half4*>(zu + (size_t)sA * 320 + t * 4);
  half4 znB = *reinterpret_cast<const half4*>(zu + (size_t)sB * 320 + t * 4);

  while (__ballot(p < pend)) {
    const bool actA = p < pend;
    const bool actB = (p + 1) < pend;
    const float4 zvA = make_float4((float)znA[0], (float)znA[1], (float)znA[2], (float)znA[3]);
    const float4 zvB = make_float4((float)znB[0], (float)znB[1], (float)znB[2], (float)znB[3]);
    sA = csrp[min(p + 2, EE - 1)].x;
    sB = csrp[min(p + 3, EE - 1)].x;
    znA = *reinterpret_cast<const half4*>(zu + (size_t)sA * 320 + t * 4);
    znB = *reinterpret_cast<const half4*>(zu + (size_t)sB * 320 + t * 4);

    float pA0 = q[0].x * zvA.x + q[0].y * zvA.y + q[0].z * zvA.z + q[0].w * zvA.w;
    float pA1 = q[1].x * zvA.x + q[1].y * zvA.y + q[1].z * zvA.z + q[1].w * zvA.w;
    float pA2 = q[2].x * zvA.x + q[2].y * zvA.y + q[2].z * zvA.z + q[2].w * zvA.w;
    float pA3 = q[3].x * zvA.x + q[3].y * zvA.y + q[3].z * zvA.z + q[3].w * zvA.w;
    float pB0 = q[0].x * zvB.x + q[0].y * zvB.y + q[0].z * zvB.z + q[0].w * zvB.w;
    float pB1 = q[1].x * zvB.x + q[1].y * zvB.y + q[1].z * zvB.z + q[1].w * zvB.w;
    float pB2 = q[2].x * zvB.x + q[2].y * zvB.y + q[2].z * zvB.z + q[2].w * zvB.w;
    float pB3 = q[3].x * zvB.x + q[3].y * zvB.y + q[3].z * zvB.z + q[3].w * zvB.w;

    float sA0, sA1, sA2, sA3, sB0, sB1, sB2, sB3;
    reduce4(pA0, pA1, pA2, pA3, sA0, sA1, sA2, sA3);
    reduce4(pB0, pB1, pB2, pB3, sB0, sB1, sB2, sB3);

    float eA0 = actA ? __expf(fminf(sA0, 60.f)) : 0.f;
    float eA1 = actA ? __expf(fminf(sA1, 60.f)) : 0.f;
    float eA2 = actA ? __expf(fminf(sA2, 60.f)) : 0.f;
    float eA3 = actA ? __expf(fminf(sA3, 60.f)) : 0.f;
    float eB0 = actB ? __expf(fminf(sB0, 60.f)) : 0.f;
    float eB1 = actB ? __expf(fminf(sB1, 60.f)) : 0.f;
    float eB2 = actB ? __expf(fminf(sB2, 60.f)) : 0.f;
    float eB3 = actB ? __expf(fminf(sB3, 60.f)) : 0.f;

    den[0] += eA0 + eB0; den[1] += eA1 + eB1;
    den[2] += eA2 + eB2; den[3] += eA3 + eB3;
    ua[0].x += eA0 * zvA.x + eB0 * zvB.x; ua[0].y += eA0 * zvA.y + eB0 * zvB.y;
    ua[0].z += eA0 * zvA.z + eB0 * zvB.z; ua[0].w += eA0 * zvA.w + eB0 * zvB.w;
    ua[1].x += eA1 * zvA.x + eB1 * zvB.x; ua[1].y += eA1 * zvA.y + eB1 * zvB.y;
    ua[1].z += eA1 * zvA.z + eB1 * zvB.z; ua[1].w += eA1 * zvA.w + eB1 * zvB.w;
    ua[2].x += eA2 * zvA.x + eB2 * zvB.x; ua[2].y += eA2 * zvA.y + eB2 * zvB.y;
    ua[2].z += eA2 * zvA.z + eB2 * zvB.z; ua[2].w += eA2 * zvA.w + eB2 * zvB.w;
    ua[3].x += eA3 * zvA.x + eB3 * zvB.x; ua[3].y += eA3 * zvA.y + eB3 * zvB.y;
    ua[3].z += eA3 * zvA.z + eB3 * zvB.z; ua[3].w += eA3 * zvA.w + eB3 * zvB.w;
    p += 2;
  }

  if (valid) {
#pragma unroll
    for (int h = 0; h < 4; ++h) {
      float inv = 1.0f / (den[h] + 1e-16f);
      half4 o;
      o[0] = (_Float16)(ua[h].x * inv);
      o[1] = (_Float16)(ua[h].y * inv);
      o[2] = (_Float16)(ua[h].z * inv);
      o[3] = (_Float16)(ua[h].w * inv);
      *reinterpret_cast<half4*>(zu + (size_t)dst * 320 + 64 + h * 64 + t * 4) = o;
    }
  }
}

}  // namespace

extern "C" void kernel_launch(void* const* d_in, const int* in_sizes, int n_in,
                              void* d_out, int out_size, void* d_ws, size_t ws_size,
                              hipStream_t stream) {
  const float* x   = (const float*)d_in[0];
  const int*   ei  = (const int*)d_in[1];
  const float* ew  = (const float*)d_in[2];
  const float* W1  = (const float*)d_in[3];
  const float* b1  = (const float*)d_in[4];
  const float* g1  = (const float*)d_in[5];
  const float* be1 = (const float*)d_in[6];
  const float* m1  = (const float*)d_in[7];
  const float* v1  = (const float*)d_in[8];
  const float* W2  = (const float*)d_in[9];
  const float* b2  = (const float*)d_in[10];
  const float* g2  = (const float*)d_in[11];
  const float* be2 = (const float*)d_in[12];
  const float* m2  = (const float*)d_in[13];
  const float* v2  = (const float*)d_in[14];
  const float* Wq  = (const float*)d_in[15];
  const float* bq  = (const float*)d_in[16];
  const float* Wk  = (const float*)d_in[17];
  const float* Wv  = (const float*)d_in[19];
  const float* bv  = (const float*)d_in[20];
  const float* Wsk = (const float*)d_in[21];
  const float* bsk = (const float*)d_in[22];
  const float* gt  = (const float*)d_in[23];
  const float* bet = (const float*)d_in[24];
  const float* mt  = (const float*)d_in[25];
  const float* vt  = (const float*)d_in[26];
  const float* Wfc = (const float*)d_in[27];
  const float* bfc = (const float*)d_in[28];

  constexpr int NP = 50048;  // padded N
  float* ws = (float*)d_ws;
  float* dinv    = ws;                           // NP (deg then dinv)
  int*   cnt     = (int*)(dinv + NP);            // NP
  int*   rank    = cnt + NP;                     // EE
  int*   ro      = rank + EE;                    // NP (N+1 used)
  int*   perm    = ro + NP;                      // NP
  int*   part    = perm + NP;                    // NP
  int*   bsum    = part + NP;                    // 256
  int2*  csrp    = (int2*)(bsum + 256);          // EE int2
  int*   blkhist = (int*)(csrp + EE);            // PBLK*64
  int*   blkoff  = blkhist + PBLK * 64;          // PBLK*64
  float* cvec    = (float*)(blkoff + PBLK * 64 + 64);  // 256
  float* bcomb   = cvec + 256;                   // 64
  _Float16* Mcp   = (_Float16*)(bcomb + 64);     // 256*64
  _Float16* Bcatp = Mcp + 256 * 64;              // 64*320
  _Float16* W1p   = Bcatp + 64 * 320;            // 128*512
  _Float16* W2p   = W1p + 128 * 512;             // 64*128
  _Float16* Wfcp  = W2p + 64 * 128;              // 32*64
  _Float16* h1f   = Wfcp + 32 * 64;              // NP*128
  _Float16* a1f   = h1f + (size_t)NP * 128;      // NP*128
  _Float16* h2f   = a1f + (size_t)NP * 128;      // NP*64
  _Float16* zuf   = h2f + (size_t)NP * 64;       // NP*320
  _Float16* qppf  = zuf + (size_t)NP * 320;      // NP*256

  const int tb = 256;

  // init: cnt/deg zero + W1 -> f16
  k_init0<<<INITB, tb, 0, stream>>>(cnt, dinv, W1, W1p);

  // GEMM1 (2-deep pipe) || edge pass (rank + weighted deg) || weight prep
  k_edgegemm1<<<GM + EDGEB + PREPB2, 256, 0, stream>>>(
      x, W1p, h1f, NN, ei, ew, cnt, dinv, rank,
      Wq, Wk, bq, Wv, bv, bsk, W2, Wsk, Wfc,
      Mcp, cvec, Bcatp, bcomb, W2p, Wfcp);

  k_node1<<<PBLK, 256, 0, stream>>>(cnt, dinv, part, bsum, blkhist);
  k_small<<<1, 256, 0, stream>>>(bsum, ro, blkhist, blkoff);

  // node2 (ro finalize + perm) || CSR fill (ro computed on the fly)
  k_nodefill<<<PBLK + EDGEB, 256, 0, stream>>>(part, bsum, ro, cnt, blkoff, perm,
                                               ei, ew, rank, csrp);

  k_gcn128<<<cdiv(NN, 4), 256, 0, stream>>>(ro, csrp, perm, h1f, dinv,
                                            b1, g1, be1, m1, v1, a1f);
  // GCN layer 2
  hgemm<64, 128, 128, false, false><<<GM, 256, 0, stream>>>(a1f, W2p, nullptr, h2f, NN);
  k_gcn64<<<cdiv(NN, 4), 256, 0, stream>>>(ro, csrp, perm, h2f, dinv,
                                           b2, g2, be2, m2, v2, zuf);

  // TransformerConv
  hgemm<256, 64, 320, false, false><<<GM, 256, 0, stream>>>(zuf, Mcp, cvec, qppf, NN);
  k_attn<<<cdiv(NN, 16), 256, 0, stream>>>(ro, csrp, perm, zuf, qppf);

  // fused epilogue
  k_aggfc<<<GM, 256, 0, stream>>>(zuf, Bcatp, bcomb, Wfcp, bfc, (float*)d_out, NN,
                                  gt, bet, mt, vt);
}

// Round 20
// 194.349 us; speedup vs baseline: 1.0745x; 1.0745x over previous
//
#include <hip/hip_runtime.h>
#include <math.h>

namespace {

constexpr int NN = 50000;
constexpr int EE = 400000;
constexpr int CIN = 512;
constexpr int GH = 128;
constexpr int GO = 64;
constexpr int HEADS = 4;
constexpr int COUT = 32;
constexpr float EPS = 1e-5f;
constexpr int PBLK = (NN + 255) / 256;   // 196 = 4*49
constexpr int EDGEB = (EE + 255) / 256;  // 1563
constexpr int GM = (NN + 63) / 64;       // 782
constexpr int PREPB2 = 128 + 56;         // Mc(64) + Bv(64) + {W2,Wsk,Wfc}(56)
constexpr int INITB = PBLK + 256;        // cnt-zero + W1 convert

typedef __attribute__((ext_vector_type(8))) _Float16 half8;
typedef __attribute__((ext_vector_type(4))) _Float16 half4;
typedef __attribute__((ext_vector_type(2))) _Float16 half2v;
typedef __attribute__((ext_vector_type(4))) float f32x4;

inline int cdiv(int a, int b) { return (a + b - 1) / b; }

// ---- init: zero cnt + convert W1 -> W1p (f16 transposed) ----------------
__global__ void k_init0(int* __restrict__ cnt, const float* __restrict__ W1,
                        _Float16* __restrict__ W1p) {
  if (blockIdx.x < PBLK) {
    int i = blockIdx.x * 256 + threadIdx.x;
    if (i < NN) cnt[i] = 0;
  } else {
    int i = (blockIdx.x - PBLK) * 256 + threadIdx.x;  // < 65536
    int k = i >> 7, f = i & 127;
    W1p[f * 512 + k] = (_Float16)W1[i];
  }
}

// ---- weight-prep device body (W1 excluded; done in k_init0) -------------
__device__ __forceinline__ void prep_body(
    int b, int tid,
    const float* __restrict__ Wq, const float* __restrict__ Wk,
    const float* __restrict__ bq, const float* __restrict__ Wv,
    const float* __restrict__ bv, const float* __restrict__ bsk,
    const float* __restrict__ W2, const float* __restrict__ Wsk,
    const float* __restrict__ Wfc,
    _Float16* __restrict__ Mcp, float* __restrict__ cvec,
    _Float16* __restrict__ Bcatp, float* __restrict__ bcomb,
    _Float16* __restrict__ W2p, _Float16* __restrict__ Wfcp) {
  if (b < 64) {
    const int i = b, col = tid, h = col >> 6, j = col & 63;
    float acc = 0.f;
    for (int t = 0; t < 64; ++t)
      acc += Wq[i * 256 + h * 64 + t] * Wk[j * 256 + h * 64 + t];
    Mcp[col * 64 + i] = (_Float16)(0.125f * acc);
    if (i == 0) {
      float c = 0.f;
      for (int t = 0; t < 64; ++t) c += bq[h * 64 + t] * Wk[j * 256 + h * 64 + t];
      cvec[col] = 0.125f * c;
    }
  } else if (b < 128) {
    const int idx = (b - 64) * 256 + tid;
    const int rr = idx >> 6, t = idx & 63;
    const int h = rr >> 6, c = rr & 63;
    Bcatp[(size_t)t * 320 + 64 + rr] = (_Float16)(0.25f * Wv[c * 256 + h * 64 + t]);
    if (b == 64 && tid < 64) {
      float s = 0.f;
#pragma unroll
      for (int h2 = 0; h2 < 4; ++h2) s += bv[h2 * 64 + tid];
      bcomb[tid] = bsk[tid] + 0.25f * s;
    }
  } else {
    const int i = (b - 128) * 256 + tid;  // < 14336
    if (i < 8192) { int k = i >> 6, f = i & 63; W2p[f * 128 + k] = (_Float16)W2[i]; }
    else if (i < 12288) { int rel = i - 8192; int k = rel >> 6, f = rel & 63; Bcatp[f * 320 + k] = (_Float16)Wsk[rel]; }
    else { int rel = i - 12288; int k = rel >> 5, f = rel & 31; Wfcp[f * 64 + k] = (_Float16)Wfc[rel]; }
  }
}

// ---- hybrid MFMA GEMM body: BM=64, 2-deep ping-pong pipeline ------------
// AF32C: A fp32, converted to single f16 at LDS store (1 MFMA/product).
template <int F, int K, int LDA, bool AF32C, bool OUTF32>
__device__ __forceinline__
void hgemm_body(int bid, const void* __restrict__ Av,
                const _Float16* __restrict__ Bp, const float* __restrict__ bias,
                void* __restrict__ Cv, int M) {
  constexpr int MI = 4;
  constexpr int NR = F / 64;
  constexpr int FW = F / 4;
  constexpr int NT = K / 64;

  __shared__ _Float16 Ah[64 * 64];

  const int tid = threadIdx.x;
  const int lane = tid & 63;
  const int wc = tid >> 6;
  const int l15 = lane & 15, lhi = lane >> 4;
  const int m0 = bid * 64;
  const int r = tid >> 2, ch = tid & 3;
  const int gr = min(m0 + r, M - 1);

  f32x4 acc[MI][NR];
#pragma unroll
  for (int mi = 0; mi < MI; ++mi)
#pragma unroll
    for (int ni = 0; ni < NR; ++ni) acc[mi][ni] = (f32x4)0.0f;

  const int sbase = r * 128 + ch * 32;
  const int ssw = (r & 7) << 4;

  auto COMPUTE = [&](int k0) {
#pragma unroll
    for (int ks = 0; ks < 2; ++ks) {
      half8 ah[MI];
#pragma unroll
      for (int mi = 0; mi < MI; ++mi) {
        const int row = mi * 16 + l15;
        const int off = (row * 128 + (ks * 32 + lhi * 8) * 2) ^ ((row & 7) << 4);
        ah[mi] = *reinterpret_cast<const half8*>((const char*)Ah + off);
      }
#pragma unroll
      for (int ni = 0; ni < NR; ++ni) {
        const int col = wc * FW + ni * 16 + l15;
        const half8 bf = *reinterpret_cast<const half8*>(
            Bp + (size_t)col * K + k0 + ks * 32 + lhi * 8);
#pragma unroll
        for (int mi = 0; mi < MI; ++mi)
          acc[mi][ni] = __builtin_amdgcn_mfma_f32_16x16x32_f16(ah[mi], bf, acc[mi][ni], 0, 0, 0);
      }
    }
  };

  float xfA[16], xfB[16];
  half8 xhA0, xhA1, xhB0, xhB1;

  auto LOADA = [&](int kk) {
    if constexpr (AF32C) {
      const float4* src = reinterpret_cast<const float4*>(
          (const float*)Av + (size_t)gr * LDA + kk + ch * 16);
#pragma unroll
      for (int i = 0; i < 4; ++i) {
        float4 f = src[i];
        xfA[i * 4 + 0] = f.x; xfA[i * 4 + 1] = f.y;
        xfA[i * 4 + 2] = f.z; xfA[i * 4 + 3] = f.w;
      }
    } else {
      const half8* src = reinterpret_cast<const half8*>(
          (const _Float16*)Av + (size_t)gr * LDA + kk + ch * 16);
      xhA0 = src[0]; xhA1 = src[1];
    }
  };
  auto LOADB = [&](int kk) {
    if constexpr (AF32C) {
      const float4* src = reinterpret_cast<const float4*>(
          (const float*)Av + (size_t)gr * LDA + kk + ch * 16);
#pragma unroll
      for (int i = 0; i < 4; ++i) {
        float4 f = src[i];
        xfB[i * 4 + 0] = f.x; xfB[i * 4 + 1] = f.y;
        xfB[i * 4 + 2] = f.z; xfB[i * 4 + 3] = f.w;
      }
    } else {
      const half8* src = reinterpret_cast<const half8*>(
          (const _Float16*)Av + (size_t)gr * LDA + kk + ch * 16);
      xhB0 = src[0]; xhB1 = src[1];
    }
  };

  auto STOREA = [&]() {
    if constexpr (AF32C) {
      half8 v0, v1;
#pragma unroll
      for (int i = 0; i < 8; ++i) v0[i] = (_Float16)xfA[i];
#pragma unroll
      for (int i = 0; i < 8; ++i) v1[i] = (_Float16)xfA[8 + i];
      *reinterpret_cast<half8*>((char*)Ah + (sbase ^ ssw)) = v0;
      *reinterpret_cast<half8*>((char*)Ah + ((sbase + 16) ^ ssw)) = v1;
    } else {
      *reinterpret_cast<half8*>((char*)Ah + (sbase ^ ssw)) = xhA0;
      *reinterpret_cast<half8*>((char*)Ah + ((sbase + 16) ^ ssw)) = xhA1;
    }
  };
  auto STOREB = [&]() {
    if constexpr (AF32C) {
      half8 v0, v1;
#pragma unroll
      for (int i = 0; i < 8; ++i) v0[i] = (_Float16)xfB[i];
#pragma unroll
      for (int i = 0; i < 8; ++i) v1[i] = (_Float16)xfB[8 + i];
      *reinterpret_cast<half8*>((char*)Ah + (sbase ^ ssw)) = v0;
      *reinterpret_cast<half8*>((char*)Ah + ((sbase + 16) ^ ssw)) = v1;
    } else {
      *reinterpret_cast<half8*>((char*)Ah + (sbase ^ ssw)) = xhB0;
      *reinterpret_cast<half8*>((char*)Ah + ((sbase + 16) ^ ssw)) = xhB1;
    }
  };

  LOADA(0);
  if constexpr (NT > 1) LOADB(64);

#pragma unroll
  for (int t = 0; t < NT; ++t) {
    if ((t & 1) == 0) STOREA(); else STOREB();
    __syncthreads();
    if ((t & 1) == 0) {
      if (t + 2 < NT) LOADA((t + 2) * 64);
    } else {
      if (t + 2 < NT) LOADB((t + 2) * 64);
    }
    COMPUTE(t * 64);
    __syncthreads();
  }

#pragma unroll
  for (int ni = 0; ni < NR; ++ni) {
    const int col = wc * FW + ni * 16 + l15;
    const float bvv = bias ? bias[col] : 0.0f;
#pragma unroll
    for (int mi = 0; mi < MI; ++mi) {
#pragma unroll
      for (int rr = 0; rr < 4; ++rr) {
        const int orow = m0 + mi * 16 + lhi * 4 + rr;
        if (orow < M) {
          float val = acc[mi][ni][rr] + bvv;
          if (OUTF32)
            ((float*)Cv)[(size_t)orow * F + col] = val;
          else
            ((_Float16*)Cv)[(size_t)orow * F + col] = (_Float16)val;
        }
      }
    }
  }
}

template <int F, int K, int LDA, bool AF32C, bool OUTF32>
__launch_bounds__(256) __global__
void hgemm(const void* __restrict__ Av, const _Float16* __restrict__ Bp,
           const float* __restrict__ bias, void* __restrict__ Cv, int M) {
  hgemm_body<F, K, LDA, AF32C, OUTF32>(blockIdx.x, Av, Bp, bias, Cv, M);
}

// ---- fused: GEMM1 || edge rank pass || weight prep ----------------------
__launch_bounds__(256) __global__
void k_edgegemm1(const float* __restrict__ x, const _Float16* __restrict__ W1p,
                 _Float16* __restrict__ h1f, int M,
                 const int* __restrict__ ei, int* __restrict__ cnt,
                 int* __restrict__ rank,
                 const float* __restrict__ Wq, const float* __restrict__ Wk,
                 const float* __restrict__ bq, const float* __restrict__ Wv,
                 const float* __restrict__ bv, const float* __restrict__ bsk,
                 const float* __restrict__ W2, const float* __restrict__ Wsk,
                 const float* __restrict__ Wfc,
                 _Float16* __restrict__ Mcp, float* __restrict__ cvec,
                 _Float16* __restrict__ Bcatp, float* __restrict__ bcomb,
                 _Float16* __restrict__ W2p, _Float16* __restrict__ Wfcp) {
  if (blockIdx.x < GM) {
    hgemm_body<128, 512, 512, true, false>(blockIdx.x, x, W1p, nullptr, h1f, M);
  } else if (blockIdx.x < GM + EDGEB) {
    int e = (blockIdx.x - GM) * 256 + threadIdx.x;
    if (e < EE) {
      int d = ei[EE + e];
      rank[e] = atomicAdd(&cnt[d], 1);
    }
  } else {
    prep_body(blockIdx.x - GM - EDGEB, threadIdx.x, Wq, Wk, bq, Wv, bv, bsk,
              W2, Wsk, Wfc, Mcp, cvec, Bcatp, bcomb, W2p, Wfcp);
  }
}

// ---- fused node pass 1: block-scan partials + block histogram -----------
__global__ void k_node1(const int* __restrict__ cnt, int* __restrict__ part,
                        int* __restrict__ bsum, int* __restrict__ blkhist) {
  __shared__ int wsm[4];
  __shared__ int lh[64];
  const int tid = threadIdx.x, lane = tid & 63, wv = tid >> 6;
  const int i = blockIdx.x * 256 + tid;
  if (tid < 64) lh[tid] = 0;
  __syncthreads();
  int v = (i < NN) ? cnt[i] : 0;
  if (i < NN) atomicAdd(&lh[min(v, 63)], 1);
  int x = v;
#pragma unroll
  for (int s = 1; s < 64; s <<= 1) {
    int t = __shfl_up(x, s);
    if (lane >= s) x += t;
  }
  if (lane == 63) wsm[wv] = x;
  __syncthreads();
  if (tid == 0) {
    int r = 0;
#pragma unroll
    for (int j = 0; j < 4; ++j) { int t = wsm[j]; wsm[j] = r; r += t; }
    bsum[blockIdx.x] = r;
  }
  __syncthreads();
  if (i < NN) part[i] = wsm[wv] + x - v;
  if (tid < 64) blkhist[blockIdx.x * 64 + tid] = lh[tid];
}

// ---- fused small pass ---------------------------------------------------
__launch_bounds__(256) __global__
void k_small(int* __restrict__ bsum, int* __restrict__ ro,
             const int* __restrict__ blkhist, int* __restrict__ blkoff) {
  __shared__ int wsm[4];
  __shared__ int qsum[4][64];
  const int tid = threadIdx.x, lane = tid & 63, wv = tid >> 6;
  {
    int v = (tid < PBLK) ? bsum[tid] : 0;
    int x = v;
#pragma unroll
    for (int s = 1; s < 64; s <<= 1) {
      int t = __shfl_up(x, s);
      if (lane >= s) x += t;
    }
    if (lane == 63) wsm[wv] = x;
    __syncthreads();
    if (tid == 0) {
      int r = 0;
#pragma unroll
      for (int j = 0; j < 4; ++j) { int t = wsm[j]; wsm[j] = r; r += t; }
      ro[NN] = r;
    }
    __syncthreads();
    if (tid < PBLK) bsum[tid] = wsm[wv] + x - v;
  }
  const int c0 = wv * 49, c1 = c0 + 49;
  {
    int qs = 0;
    int k = c0;
    for (; k + 4 <= c1; k += 4) {
      int a = blkhist[(k + 0) * 64 + lane];
      int b = blkhist[(k + 1) * 64 + lane];
      int c = blkhist[(k + 2) * 64 + lane];
      int d = blkhist[(k + 3) * 64 + lane];
      qs += (a + b) + (c + d);
    }
    for (; k < c1; ++k) qs += blkhist[k * 64 + lane];
    qsum[wv][lane] = qs;
  }
  __syncthreads();
  int tot = qsum[0][lane] + qsum[1][lane] + qsum[2][lane] + qsum[3][lane];
  int x = tot;
#pragma unroll
  for (int s = 1; s < 64; s <<= 1) {
    int t = __shfl_up(x, s);
    if (lane >= s) x += t;
  }
  int run = x - tot;
  for (int q = 0; q < wv; ++q) run += qsum[q][lane];
  int k = c0;
  for (; k + 4 <= c1; k += 4) {
    int a = blkhist[(k + 0) * 64 + lane];
    int b = blkhist[(k + 1) * 64 + lane];
    int c = blkhist[(k + 2) * 64 + lane];
    int d = blkhist[(k + 3) * 64 + lane];
    blkoff[(k + 0) * 64 + lane] = run;
    blkoff[(k + 1) * 64 + lane] = run + a;
    blkoff[(k + 2) * 64 + lane] = run + a + b;
    blkoff[(k + 3) * 64 + lane] = run + a + b + c;
    run += (a + b) + (c + d);
  }
  for (; k < c1; ++k) {
    int c = blkhist[k * 64 + lane];
    blkoff[k * 64 + lane] = run;
    run += c;
  }
}

// ---- fused: node2 (ro finalize + perm) || CSR fill (on-the-fly ro) ------
__launch_bounds__(256) __global__
void k_nodefill(const int* __restrict__ part, const int* __restrict__ bsum,
                int* __restrict__ ro, const int* __restrict__ cnt,
                const int* __restrict__ blkoff, int* __restrict__ perm,
                const int* __restrict__ ei, const float* __restrict__ w,
                const int* __restrict__ rank, int2* __restrict__ csrp) {
  if (blockIdx.x < PBLK) {
    __shared__ int lcur[64];
    const int tid = threadIdx.x;
    const int i = blockIdx.x * 256 + tid;
    if (tid < 64) lcur[tid] = 0;
    if (i < NN) ro[i] = part[i] + bsum[i >> 8];
    __syncthreads();
    if (i < NN) {
      int b = min(cnt[i], 63);
      int r = atomicAdd(&lcur[b], 1);
      perm[blkoff[blockIdx.x * 64 + b] + r] = i;
    }
  } else {
    int e = (blockIdx.x - PBLK) * 256 + threadIdx.x;
    if (e < EE) {
      int d = ei[EE + e];
      int p = part[d] + bsum[d >> 8] + rank[e];
      int2 pk;
      pk.x = ei[e];
      pk.y = __float_as_int(w[e]);
      csrp[p] = pk;
    }
  }
}

// ---- deg/dinv: thread per dst, sum w over its CSR segment ---------------
__global__ void k_deg(const int* __restrict__ ro, const int2* __restrict__ csrp,
                      float* __restrict__ dinv) {
  int d = blockIdx.x * 256 + threadIdx.x;
  if (d >= NN) return;
  int p = ro[d];
  const int p1 = ro[d + 1];
  float s0 = 0.f, s1 = 0.f, s2 = 0.f, s3 = 0.f;
  for (; p + 4 <= p1; p += 4) {
    int2 a = csrp[p], b = csrp[p + 1], c = csrp[p + 2], e = csrp[p + 3];
    s0 += __int_as_float(a.y); s1 += __int_as_float(b.y);
    s2 += __int_as_float(c.y); s3 += __int_as_float(e.y);
  }
  for (; p < p1; ++p) s0 += __int_as_float(csrp[p].y);
  dinv[d] = rsqrtf(1.0f + (s0 + s1) + (s2 + s3));
}

// ---- fused final: agg = [z|u]@Bcat + bcomb, BN+ReLU; out = agg@Wfc + bfc
__launch_bounds__(256) __global__
void k_aggfc(const _Float16* __restrict__ zu, const _Float16* __restrict__ Bcatp,
             const float* __restrict__ bcomb, const _Float16* __restrict__ Wfcp,
             const float* __restrict__ bfc, float* __restrict__ out, int M,
             const float* __restrict__ gt, const float* __restrict__ bet,
             const float* __restrict__ mt, const float* __restrict__ vt) {
  __shared__ _Float16 Ah[64 * 64];
  __shared__ _Float16 Gs[64 * 64];

  const int tid = threadIdx.x;
  const int lane = tid & 63;
  const int wid = tid >> 6;
  const int l15 = lane & 15, lhi = lane >> 4;
  const int m0 = blockIdx.x * 64;
  const int r = tid >> 2, ch = tid & 3;
  const int gr = min(m0 + r, M - 1);

  f32x4 acc[4];
#pragma unroll
  for (int mi = 0; mi < 4; ++mi) acc[mi] = (f32x4)0.0f;

  half8 xhA0, xhA1, xhB0, xhB1;
  auto LOADA = [&](int kk) {
    const half8* src = reinterpret_cast<const half8*>(
        zu + (size_t)gr * 320 + kk + ch * 16);
    xhA0 = src[0]; xhA1 = src[1];
  };
  auto LOADB = [&](int kk) {
    const half8* src = reinterpret_cast<const half8*>(
        zu + (size_t)gr * 320 + kk + ch * 16);
    xhB0 = src[0]; xhB1 = src[1];
  };
  const int sbase = r * 128 + ch * 32;
  const int ssw = (r & 7) << 4;
  auto STOREA = [&]() {
    *reinterpret_cast<half8*>((char*)Ah + (sbase ^ ssw)) = xhA0;
    *reinterpret_cast<half8*>((char*)Ah + ((sbase + 16) ^ ssw)) = xhA1;
  };
  auto STOREB = [&]() {
    *reinterpret_cast<half8*>((char*)Ah + (sbase ^ ssw)) = xhB0;
    *reinterpret_cast<half8*>((char*)Ah + ((sbase + 16) ^ ssw)) = xhB1;
  };

  LOADA(0);
  LOADB(64);
#pragma unroll
  for (int t = 0; t < 5; ++t) {
    if ((t & 1) == 0) STOREA(); else STOREB();
    __syncthreads();
    if ((t & 1) == 0) {
      if (t + 2 < 5) LOADA((t + 2) * 64);
    } else {
      if (t + 2 < 5) LOADB((t + 2) * 64);
    }
    const int k0 = t * 64;
#pragma unroll
    for (int ks = 0; ks < 2; ++ks) {
      half8 ah[4];
#pragma unroll
      for (int mi = 0; mi < 4; ++mi) {
        const int row = mi * 16 + l15;
        const int off = (row * 128 + (ks * 32 + lhi * 8) * 2) ^ ((row & 7) << 4);
        ah[mi] = *reinterpret_cast<const half8*>((const char*)Ah + off);
      }
      const int col = wid * 16 + l15;
      const half8 bf = *reinterpret_cast<const half8*>(
          Bcatp + (size_t)col * 320 + k0 + ks * 32 + lhi * 8);
#pragma unroll
      for (int mi = 0; mi < 4; ++mi)
        acc[mi] = __builtin_amdgcn_mfma_f32_16x16x32_f16(ah[mi], bf, acc[mi], 0, 0, 0);
    }
    __syncthreads();
  }

  {
    const int col = wid * 16 + l15;
    const float bns = gt[col] * rsqrtf(vt[col] + EPS);
    const float bnb = bet[col], bnm = mt[col], bco = bcomb[col];
#pragma unroll
    for (int mi = 0; mi < 4; ++mi) {
#pragma unroll
      for (int rr = 0; rr < 4; ++rr) {
        const int row = mi * 16 + lhi * 4 + rr;
        float val = acc[mi][rr] + bco;
        val = (val - bnm) * bns + bnb;
        val = val > 0.f ? val : 0.f;
        const int boff = (row * 128 + col * 2) ^ ((row & 7) << 4);
        *reinterpret_cast<_Float16*>((char*)Gs + boff) = (_Float16)val;
      }
    }
  }
  __syncthreads();

  f32x4 acc2[2];
#pragma unroll
  for (int ni = 0; ni < 2; ++ni) acc2[ni] = (f32x4)0.0f;
#pragma unroll
  for (int ks = 0; ks < 2; ++ks) {
    const int row = wid * 16 + l15;
    const int off = (row * 128 + (ks * 32 + lhi * 8) * 2) ^ ((row & 7) << 4);
    const half8 ag = *reinterpret_cast<const half8*>((const char*)Gs + off);
#pragma unroll
    for (int ni = 0; ni < 2; ++ni) {
      const int col = ni * 16 + l15;
      const half8 bf = *reinterpret_cast<const half8*>(
          Wfcp + (size_t)col * 64 + ks * 32 + lhi * 8);
      acc2[ni] = __builtin_amdgcn_mfma_f32_16x16x32_f16(ag, bf, acc2[ni], 0, 0, 0);
    }
  }
#pragma unroll
  for (int ni = 0; ni < 2; ++ni) {
    const int col = ni * 16 + l15;
#pragma unroll
    for (int rr = 0; rr < 4; ++rr) {
      const int orow = m0 + wid * 16 + lhi * 4 + rr;
      if (orow < M) out[(size_t)orow * COUT + col] = acc2[ni][rr] + bfc[col];
    }
  }
}

// ---- GCN propagate: on-the-fly norm (dinv[s]*w), final scale by dinv[d] -
__launch_bounds__(256) __global__
void k_gcn128(const int* __restrict__ ro, const int2* __restrict__ csrp,
              const int* __restrict__ perm, const _Float16* __restrict__ h,
              const float* __restrict__ dinv, const float* __restrict__ bias,
              const float* __restrict__ g, const float* __restrict__ be,
              const float* __restrict__ m, const float* __restrict__ v,
              _Float16* __restrict__ out) {
  const int idx = blockIdx.x * 4 + (threadIdx.x >> 6);
  const int lane = threadIdx.x & 63;
  if (idx >= NN) return;
  const int wid = perm[idx];
  const float di = dinv[wid];
  const int p0 = ro[wid], p1 = ro[wid + 1];

  half2v sv = *reinterpret_cast<const half2v*>(h + (size_t)wid * 128 + lane * 2);
  float2 a[4];
  a[0] = make_float2((float)sv[0] * di, (float)sv[1] * di);
  a[1] = make_float2(0.f, 0.f);
  a[2] = make_float2(0.f, 0.f);
  a[3] = make_float2(0.f, 0.f);
  int p = p0;
  for (; p + 8 <= p1; p += 8) {
    int2 pk[8];
#pragma unroll
    for (int j = 0; j < 8; ++j) pk[j] = csrp[p + j];
    float ds[8];
#pragma unroll
    for (int j = 0; j < 8; ++j) ds[j] = dinv[pk[j].x];
    half2v hv[8];
#pragma unroll
    for (int j = 0; j < 8; ++j)
      hv[j] = *reinterpret_cast<const half2v*>(h + (size_t)pk[j].x * 128 + lane * 2);
#pragma unroll
    for (int j = 0; j < 8; ++j) {
      float c = ds[j] * __int_as_float(pk[j].y);
      a[j & 3].x += c * (float)hv[j][0];
      a[j & 3].y += c * (float)hv[j][1];
    }
  }
  for (; p + 4 <= p1; p += 4) {
    int2 pk[4];
#pragma unroll
    for (int j = 0; j < 4; ++j) pk[j] = csrp[p + j];
    float ds[4];
#pragma unroll
    for (int j = 0; j < 4; ++j) ds[j] = dinv[pk[j].x];
    half2v hv[4];
#pragma unroll
    for (int j = 0; j < 4; ++j)
      hv[j] = *reinterpret_cast<const half2v*>(h + (size_t)pk[j].x * 128 + lane * 2);
#pragma unroll
    for (int j = 0; j < 4; ++j) {
      float c = ds[j] * __int_as_float(pk[j].y);
      a[j].x += c * (float)hv[j][0];
      a[j].y += c * (float)hv[j][1];
    }
  }
  for (; p < p1; ++p) {
    int2 pk = csrp[p];
    float c = dinv[pk.x] * __int_as_float(pk.y);
    half2v hv = *reinterpret_cast<const half2v*>(h + (size_t)pk.x * 128 + lane * 2);
    a[1].x += c * (float)hv[0]; a[1].y += c * (float)hv[1];
  }
  float ax = ((a[0].x + a[1].x) + (a[2].x + a[3].x)) * di;
  float ay = ((a[0].y + a[1].y) + (a[2].y + a[3].y)) * di;
  float2 gg = reinterpret_cast<const float2*>(g)[lane];
  float2 bb = reinterpret_cast<const float2*>(be)[lane];
  float2 mm = reinterpret_cast<const float2*>(m)[lane];
  float2 vv = reinterpret_cast<const float2*>(v)[lane];
  float2 bi = reinterpret_cast<const float2*>(bias)[lane];
  float s0 = gg.x * rsqrtf(vv.x + EPS);
  float s1 = gg.y * rsqrtf(vv.y + EPS);
  float y0 = (ax + bi.x - mm.x) * s0 + bb.x;
  float y1 = (ay + bi.y - mm.y) * s1 + bb.y;
  half2v o;
  o[0] = (_Float16)(y0 > 0.f ? y0 : 0.f);
  o[1] = (_Float16)(y1 > 0.f ? y1 : 0.f);
  *reinterpret_cast<half2v*>(out + (size_t)wid * 128 + lane * 2) = o;
}

// F=64 variant: writes z into zu[:,0:64] (stride 320)
__launch_bounds__(256) __global__
void k_gcn64(const int* __restrict__ ro, const int2* __restrict__ csrp,
             const int* __restrict__ perm, const _Float16* __restrict__ h,
             const float* __restrict__ dinv, const float* __restrict__ bias,
             const float* __restrict__ g, const float* __restrict__ be,
             const float* __restrict__ m, const float* __restrict__ v,
             _Float16* __restrict__ zu) {
  const int idx = blockIdx.x * 4 + (threadIdx.x >> 6);
  const int lane = threadIdx.x & 63;
  if (idx >= NN) return;
  const int wid = perm[idx];
  const float di = dinv[wid];
  const int p0 = ro[wid], p1 = ro[wid + 1];

  float a[4];
  a[0] = (float)h[(size_t)wid * 64 + lane] * di;
  a[1] = 0.f; a[2] = 0.f; a[3] = 0.f;
  int p = p0;
  for (; p + 8 <= p1; p += 8) {
    int2 pk[8];
#pragma unroll
    for (int j = 0; j < 8; ++j) pk[j] = csrp[p + j];
    float ds[8];
#pragma unroll
    for (int j = 0; j < 8; ++j) ds[j] = dinv[pk[j].x];
    float hv[8];
#pragma unroll
    for (int j = 0; j < 8; ++j) hv[j] = (float)h[(size_t)pk[j].x * 64 + lane];
#pragma unroll
    for (int j = 0; j < 8; ++j) a[j & 3] += ds[j] * __int_as_float(pk[j].y) * hv[j];
  }
  for (; p + 4 <= p1; p += 4) {
    int2 pk[4];
#pragma unroll
    for (int j = 0; j < 4; ++j) pk[j] = csrp[p + j];
    float ds[4];
#pragma unroll
    for (int j = 0; j < 4; ++j) ds[j] = dinv[pk[j].x];
    float hv[4];
#pragma unroll
    for (int j = 0; j < 4; ++j) hv[j] = (float)h[(size_t)pk[j].x * 64 + lane];
#pragma unroll
    for (int j = 0; j < 4; ++j) a[j] += ds[j] * __int_as_float(pk[j].y) * hv[j];
  }
  for (; p < p1; ++p) {
    int2 pk = csrp[p];
    a[1] += dinv[pk.x] * __int_as_float(pk.y) * (float)h[(size_t)pk.x * 64 + lane];
  }
  float av = ((a[0] + a[1]) + (a[2] + a[3])) * di;
  float sc = g[lane] * rsqrtf(v[lane] + EPS);
  float y = (av + bias[lane] - m[lane]) * sc + be[lane];
  zu[(size_t)wid * 320 + lane] = (_Float16)(y > 0.f ? y : 0.f);
}

// ---- fused edge-softmax attention, 2-wide software pipeline -------------
__launch_bounds__(256) __global__
void k_attn(const int* __restrict__ ro, const int2* __restrict__ csrp,
            const int* __restrict__ perm, _Float16* zu,
            const _Float16* __restrict__ qpp) {
  const int wave = blockIdx.x * 4 + (threadIdx.x >> 6);
  const int lane = threadIdx.x & 63;
  const int g = lane >> 4;
  const int t = lane & 15;
  const bool bit3 = (t & 8) != 0, bit2 = (t & 4) != 0;

  const int idx = wave * 4 + g;
  const bool valid = idx < NN;
  const int dst = perm[valid ? idx : 0];

  float4 q[4];
#pragma unroll
  for (int h = 0; h < 4; ++h) {
    half4 qh = *reinterpret_cast<const half4*>(qpp + (size_t)dst * 256 + h * 64 + t * 4);
    q[h] = make_float4((float)qh[0], (float)qh[1], (float)qh[2], (float)qh[3]);
  }

  float4 ua[4];
  float den[4];
#pragma unroll
  for (int h = 0; h < 4; ++h) {
    ua[h] = make_float4(0.f, 0.f, 0.f, 0.f);
    den[h] = 0.f;
  }

  int p = valid ? ro[dst] : 0;
  const int pend = valid ? ro[dst + 1] : 0;

  auto reduce4 = [&](float pa0, float pa1, float pa2, float pa3,
                     float& o0, float& o1, float& o2, float& o3) {
    float send1 = bit3 ? pa0 : pa2;
    float recv1 = __shfl_xor(send1, 8);
    float a0 = (bit3 ? pa2 : pa0) + recv1;
    float send2 = bit3 ? pa1 : pa3;
    float recv2 = __shfl_xor(send2, 8);
    float a1 = (bit3 ? pa3 : pa1) + recv2;
    float send3 = bit2 ? a0 : a1;
    float recv3 = __shfl_xor(send3, 4);
    float b = (bit2 ? a1 : a0) + recv3;
    b += __shfl_xor(b, 2);
    b += __shfl_xor(b, 1);
    float r4 = __shfl_xor(b, 4);
    float r8 = __shfl_xor(b, 8);
    float r84 = __shfl_xor(r4, 8);
    o0 = bit3 ? (bit2 ? r84 : r8) : (bit2 ? r4 : b);
    o1 = bit3 ? (bit2 ? r8 : r84) : (bit2 ? b : r4);
    o2 = bit3 ? (bit2 ? r4 : b) : (bit2 ? r84 : r8);
    o3 = bit3 ? (bit2 ? b : r4) : (bit2 ? r8 : r84);
  };

  int sA = csrp[min(p, EE - 1)].x;
  int sB = csrp[min(p + 1, EE - 1)].x;
  half4 znA = *reinterpret_cast<const half4*>(zu + (size_t)sA * 320 + t * 4);
  half4 znB = *reinterpret_cast<const half4*>(zu + (size_t)sB * 320 + t * 4);

  while (__ballot(p < pend)) {
    const bool actA = p < pend;
    const bool actB = (p + 1) < pend;
    const float4 zvA = make_float4((float)znA[0], (float)znA[1], (float)znA[2], (float)znA[3]);
    const float4 zvB = make_float4((float)znB[0], (float)znB[1], (float)znB[2], (float)znB[3]);
    sA = csrp[min(p + 2, EE - 1)].x;
    sB = csrp[min(p + 3, EE - 1)].x;
    znA = *reinterpret_cast<const half4*>(zu + (size_t)sA * 320 + t * 4);
    znB = *reinterpret_cast<const half4*>(zu + (size_t)sB * 320 + t * 4);

    float pA0 = q[0].x * zvA.x + q[0].y * zvA.y + q[0].z * zvA.z + q[0].w * zvA.w;
    float pA1 = q[1].x * zvA.x + q[1].y * zvA.y + q[1].z * zvA.z + q[1].w * zvA.w;
    float pA2 = q[2].x * zvA.x + q[2].y * zvA.y + q[2].z * zvA.z + q[2].w * zvA.w;
    float pA3 = q[3].x * zvA.x + q[3].y * zvA.y + q[3].z * zvA.z + q[3].w * zvA.w;
    float pB0 = q[0].x * zvB.x + q[0].y * zvB.y + q[0].z * zvB.z + q[0].w * zvB.w;
    float pB1 = q[1].x * zvB.x + q[1].y * zvB.y + q[1].z * zvB.z + q[1].w * zvB.w;
    float pB2 = q[2].x * zvB.x + q[2].y * zvB.y + q[2].z * zvB.z + q[2].w * zvB.w;
    float pB3 = q[3].x * zvB.x + q[3].y * zvB.y + q[3].z * zvB.z + q[3].w * zvB.w;

    float sA0, sA1, sA2, sA3, sB0, sB1, sB2, sB3;
    reduce4(pA0, pA1, pA2, pA3, sA0, sA1, sA2, sA3);
    reduce4(pB0, pB1, pB2, pB3, sB0, sB1, sB2, sB3);

    float eA0 = actA ? __expf(fminf(sA0, 60.f)) : 0.f;
    float eA1 = actA ? __expf(fminf(sA1, 60.f)) : 0.f;
    float eA2 = actA ? __expf(fminf(sA2, 60.f)) : 0.f;
    float eA3 = actA ? __expf(fminf(sA3, 60.f)) : 0.f;
    float eB0 = actB ? __expf(fminf(sB0, 60.f)) : 0.f;
    float eB1 = actB ? __expf(fminf(sB1, 60.f)) : 0.f;
    float eB2 = actB ? __expf(fminf(sB2, 60.f)) : 0.f;
    float eB3 = actB ? __expf(fminf(sB3, 60.f)) : 0.f;

    den[0] += eA0 + eB0; den[1] += eA1 + eB1;
    den[2] += eA2 + eB2; den[3] += eA3 + eB3;
    ua[0].x += eA0 * zvA.x + eB0 * zvB.x; ua[0].y += eA0 * zvA.y + eB0 * zvB.y;
    ua[0].z += eA0 * zvA.z + eB0 * zvB.z; ua[0].w += eA0 * zvA.w + eB0 * zvB.w;
    ua[1].x += eA1 * zvA.x + eB1 * zvB.x; ua[1].y += eA1 * zvA.y + eB1 * zvB.y;
    ua[1].z += eA1 * zvA.z + eB1 * zvB.z; ua[1].w += eA1 * zvA.w + eB1 * zvB.w;
    ua[2].x += eA2 * zvA.x + eB2 * zvB.x; ua[2].y += eA2 * zvA.y + eB2 * zvB.y;
    ua[2].z += eA2 * zvA.z + eB2 * zvB.z; ua[2].w += eA2 * zvA.w + eB2 * zvB.w;
    ua[3].x += eA3 * zvA.x + eB3 * zvB.x; ua[3].y += eA3 * zvA.y + eB3 * zvB.y;
    ua[3].z += eA3 * zvA.z + eB3 * zvB.z; ua[3].w += eA3 * zvA.w + eB3 * zvB.w;
    p += 2;
  }

  if (valid) {
#pragma unroll
    for (int h = 0; h < 4; ++h) {
      float inv = 1.0f / (den[h] + 1e-16f);
      half4 o;
      o[0] = (_Float16)(ua[h].x * inv);
      o[1] = (_Float16)(ua[h].y * inv);
      o[2] = (_Float16)(ua[h].z * inv);
      o[3] = (_Float16)(ua[h].w * inv);
      *reinterpret_cast<half4*>(zu + (size_t)dst * 320 + 64 + h * 64 + t * 4) = o;
    }
  }
}

}  // namespace

extern "C" void kernel_launch(void* const* d_in, const int* in_sizes, int n_in,
                              void* d_out, int out_size, void* d_ws, size_t ws_size,
                              hipStream_t stream) {
  const float* x   = (const float*)d_in[0];
  const int*   ei  = (const int*)d_in[1];
  const float* ew  = (const float*)d_in[2];
  const float* W1  = (const float*)d_in[3];
  const float* b1  = (const float*)d_in[4];
  const float* g1  = (const float*)d_in[5];
  const float* be1 = (const float*)d_in[6];
  const float* m1  = (const float*)d_in[7];
  const float* v1  = (const float*)d_in[8];
  const float* W2  = (const float*)d_in[9];
  const float* b2  = (const float*)d_in[10];
  const float* g2  = (const float*)d_in[11];
  const float* be2 = (const float*)d_in[12];
  const float* m2  = (const float*)d_in[13];
  const float* v2  = (const float*)d_in[14];
  const float* Wq  = (const float*)d_in[15];
  const float* bq  = (const float*)d_in[16];
  const float* Wk  = (const float*)d_in[17];
  const float* Wv  = (const float*)d_in[19];
  const float* bv  = (const float*)d_in[20];
  const float* Wsk = (const float*)d_in[21];
  const float* bsk = (const float*)d_in[22];
  const float* gt  = (const float*)d_in[23];
  const float* bet = (const float*)d_in[24];
  const float* mt  = (const float*)d_in[25];
  const float* vt  = (const float*)d_in[26];
  const float* Wfc = (const float*)d_in[27];
  const float* bfc = (const float*)d_in[28];

  constexpr int NP = 50048;  // padded N
  float* ws = (float*)d_ws;
  float* dinv    = ws;                           // NP
  int*   cnt     = (int*)(dinv + NP);            // NP
  int*   rank    = cnt + NP;                     // EE
  int*   ro      = rank + EE;                    // NP (N+1 used)
  int*   perm    = ro + NP;                      // NP
  int*   part    = perm + NP;                    // NP
  int*   bsum    = part + NP;                    // 256
  int2*  csrp    = (int2*)(bsum + 256);          // EE int2
  int*   blkhist = (int*)(csrp + EE);            // PBLK*64
  int*   blkoff  = blkhist + PBLK * 64;          // PBLK*64
  float* cvec    = (float*)(blkoff + PBLK * 64 + 64);  // 256
  float* bcomb   = cvec + 256;                   // 64
  _Float16* Mcp   = (_Float16*)(bcomb + 64);     // 256*64
  _Float16* Bcatp = Mcp + 256 * 64;              // 64*320
  _Float16* W1p   = Bcatp + 64 * 320;            // 128*512
  _Float16* W2p   = W1p + 128 * 512;             // 64*128
  _Float16* Wfcp  = W2p + 64 * 128;              // 32*64
  _Float16* h1f   = Wfcp + 32 * 64;              // NP*128
  _Float16* a1f   = h1f + (size_t)NP * 128;      // NP*128
  _Float16* h2f   = a1f + (size_t)NP * 128;      // NP*64
  _Float16* zuf   = h2f + (size_t)NP * 64;       // NP*320
  _Float16* qppf  = zuf + (size_t)NP * 320;      // NP*256

  const int tb = 256;

  // init: cnt zero + W1 -> f16
  k_init0<<<INITB, tb, 0, stream>>>(cnt, W1, W1p);

  // GEMM1 (2-deep pipe) || edge rank pass || remaining weight prep
  k_edgegemm1<<<GM + EDGEB + PREPB2, 256, 0, stream>>>(
      x, W1p, h1f, NN, ei, cnt, rank,
      Wq, Wk, bq, Wv, bv, bsk, W2, Wsk, Wfc,
      Mcp, cvec, Bcatp, bcomb, W2p, Wfcp);

  k_node1<<<PBLK, 256, 0, stream>>>(cnt, part, bsum, blkhist);
  k_small<<<1, 256, 0, stream>>>(bsum, ro, blkhist, blkoff);

  // node2 (ro finalize + perm) || CSR fill (ro computed on the fly)
  k_nodefill<<<PBLK + EDGEB, 256, 0, stream>>>(part, bsum, ro, cnt, blkoff, perm,
                                               ei, ew, rank, csrp);
  // dinv from CSR (no atomics)
  k_deg<<<cdiv(NN, tb), tb, 0, stream>>>(ro, csrp, dinv);

  k_gcn128<<<cdiv(NN, 4), 256, 0, stream>>>(ro, csrp, perm, h1f, dinv,
                                            b1, g1, be1, m1, v1, a1f);
  // GCN layer 2
  hgemm<64, 128, 128, false, false><<<GM, 256, 0, stream>>>(a1f, W2p, nullptr, h2f, NN);
  k_gcn64<<<cdiv(NN, 4), 256, 0, stream>>>(ro, csrp, perm, h2f, dinv,
                                           b2, g2, be2, m2, v2, zuf);

  // TransformerConv
  hgemm<256, 64, 320, false, false><<<GM, 256, 0, stream>>>(zuf, Mcp, cvec, qppf, NN);
  k_attn<<<cdiv(NN, 16), 256, 0, stream>>>(ro, csrp, perm, zuf, qppf);

  // fused epilogue
  k_aggfc<<<GM, 256, 0, stream>>>(zuf, Bcatp, bcomb, Wfcp, bfc, (float*)d_out, NN,
                                  gt, bet, mt, vt);
}